// Round 2
// baseline (17245.485 us; speedup 1.0000x reference)
//
#include <hip/hip_runtime.h>
#include <math.h>

// ---------------------------------------------------------------------------
// Persistent-dataflow LSTM encoder-decoder.
//  enc_persistent: 256 blocks = 8 row-pipelines x 32 col-tiles, 256 steps
//                  in-kernel, atomic-flag sync (no launches per step).
//  dec_persistent: same structure, 16 pipelines (8 m-groups x 2 directions).
// ---------------------------------------------------------------------------

// ws layout (float offsets)
#define OFS_HENC   0u          // [2][256][512]
#define OFS_CENC   262144u     // [256][512]
#define OFS_HF     393216u     // [2][256][256]
#define OFS_HB     524288u     // [2][256][256]
#define OFS_CF     655360u     // [256][256]
#define OFS_CB     720896u     // [256][256]
#define OFS_Z      786432u     // [256][2048]
#define OFS_XW     1310720u    // [256][2048]
#define OFS_HSEQ   1835008u    // [256][64][512] (first 2097152 also = zpart)
#define OFS_FLAGS  10223616u   // 6144 ints used, 8192 zeroed
#define WS_FLOATS  10231808u

// flag layout (int offsets within flags region)
//  enc z_cnt : [mt*256 + t]          target 32
//  enc h_cnt : [2048 + mt*256 + t]   target 32
//  dec z_cnt : [4096 + p*64 + s]     target 16   (p = mt*2 + dir)
//  dec h_cnt : [5120 + p*64 + s]     target 16

__device__ __forceinline__ float sigm(float x) { return 1.0f / (1.0f + __expf(-x)); }

__device__ __forceinline__ int ld_acq(const int* p) {
    return __hip_atomic_load(p, __ATOMIC_ACQUIRE, __HIP_MEMORY_SCOPE_AGENT);
}
__device__ __forceinline__ void add_rel(int* p) {
    __hip_atomic_fetch_add(p, 1, __ATOMIC_RELEASE, __HIP_MEMORY_SCOPE_AGENT);
}

// ---------------------------------------------------------------------------
// 32x64 tile GEMM slab: o[2][4] += A[rows r0,r1][KT] * B[KT][4 cols]
// A row-contiguous, B row stride bld. 16-k chunks for load/FMA overlap.
// ---------------------------------------------------------------------------
__device__ __forceinline__ void gemm_slab(
    const float* __restrict__ a0p, const float* __restrict__ a1p,
    const float* __restrict__ bp, int KT, int bld, float4& o0, float4& o1)
{
    for (int kb = 0; kb < KT; kb += 16) {
        float4 A0[4], A1[4], B[16];
        #pragma unroll
        for (int g = 0; g < 4; ++g) {
            A0[g] = *(const float4*)(a0p + kb + g * 4);
            A1[g] = *(const float4*)(a1p + kb + g * 4);
        }
        #pragma unroll
        for (int q = 0; q < 16; ++q)
            B[q] = *(const float4*)(bp + (size_t)(kb + q) * bld);
        #pragma unroll
        for (int g = 0; g < 4; ++g) {
            #pragma unroll
            for (int kk = 0; kk < 4; ++kk) {
                const float4 b = B[g * 4 + kk];
                const float a0 = ((const float*)&A0[g])[kk];
                const float a1 = ((const float*)&A1[g])[kk];
                o0.x = fmaf(a0, b.x, o0.x); o0.y = fmaf(a0, b.y, o0.y);
                o0.z = fmaf(a0, b.z, o0.z); o0.w = fmaf(a0, b.w, o0.w);
                o1.x = fmaf(a1, b.x, o1.x); o1.y = fmaf(a1, b.y, o1.y);
                o1.z = fmaf(a1, b.z, o1.z); o1.w = fmaf(a1, b.w, o1.w);
            }
        }
    }
}

// block reductions (256 threads = 4 waves)
__device__ __forceinline__ float blk_max(float v, float* red) {
    #pragma unroll
    for (int m = 32; m; m >>= 1) v = fmaxf(v, __shfl_xor(v, m, 64));
    const int wid = threadIdx.x >> 6;
    if ((threadIdx.x & 63) == 0) red[wid] = v;
    __syncthreads();
    v = fmaxf(fmaxf(red[0], red[1]), fmaxf(red[2], red[3]));
    __syncthreads();
    return v;
}
__device__ __forceinline__ float blk_sum(float v, float* red) {
    #pragma unroll
    for (int m = 32; m; m >>= 1) v += __shfl_xor(v, m, 64);
    const int wid = threadIdx.x >> 6;
    if ((threadIdx.x & 63) == 0) red[wid] = v;
    __syncthreads();
    v = red[0] + red[1] + red[2] + red[3];
    __syncthreads();
    return v;
}

// ---------------------------------------------------------------------------
// Encoder: 256 blocks, (mt = bid>>5, nt = bid&31). Each block: GEMM tile
// [mt*32..+32) x [nt*64..+64), then updates row (mt*32+nt) (softmax gates).
// ---------------------------------------------------------------------------
__global__ __launch_bounds__(256) void enc_persistent(
    const float* __restrict__ x, const float* __restrict__ W,
    const float* __restrict__ U, const float* __restrict__ bias,
    float* __restrict__ henc, float* __restrict__ cenc,
    float* __restrict__ z, int* __restrict__ fl)
{
    __shared__ float red[4];
    const int bid = blockIdx.x;
    const int nt = bid & 31, mt = bid >> 5;
    const int tid = threadIdx.x;
    const int tr = tid >> 4, tc = tid & 15;
    const int r0 = mt * 32 + tr, r1 = r0 + 16;
    const int c0 = nt * 64 + tc * 4;
    int* zc = fl + mt * 256;
    int* hc = fl + 2048 + mt * 256;
    const int ur = mt * 32 + nt;                 // row this block updates

    for (int t = 0; t < 256; ++t) {
        float4 o0 = {0, 0, 0, 0}, o1 = {0, 0, 0, 0};
        // x-part first: independent of h -> hides handoff latency
        gemm_slab(x + (size_t)r0 * 16384 + t * 64,
                  x + (size_t)r1 * 16384 + t * 64, W + c0, 64, 2048, o0, o1);
        if (t > 0) {
            if (tid == 0) { while (ld_acq(hc + (t - 1)) < 32) __builtin_amdgcn_s_sleep(1); }
            __syncthreads();
        }
        const float* hp = henc + (size_t)((t + 1) & 1) * 131072;
        gemm_slab(hp + (size_t)r0 * 512, hp + (size_t)r1 * 512, U + c0, 512, 2048, o0, o1);
        *(float4*)(z + (size_t)r0 * 2048 + c0) = o0;
        *(float4*)(z + (size_t)r1 * 2048 + c0) = o1;
        __syncthreads();                          // drains stores (vmcnt0)
        if (tid == 0) { __threadfence(); add_rel(zc + t); }

        // ---- distributed gate update: one row per block ----
        if (tid == 0) { while (ld_acq(zc + t) < 32) __builtin_amdgcn_s_sleep(1); }
        __syncthreads();
        {
            const float* zr = z + (size_t)ur * 2048;
            float* hout = henc + (size_t)(t & 1) * 131072;
            const int u0 = tid, u1 = tid + 256;
            const float zg0 = zr[1024 + u0] + bias[1024 + u0];
            const float zg1 = zr[1024 + u1] + bias[1024 + u1];
            const float mx = blk_max(fmaxf(zg0, zg1), red);
            float e0 = __expf(zg0 - mx), e1 = __expf(zg1 - mx);
            const float inv = 1.0f / blk_sum(e0 + e1, red);
            const float zi0 = zr[u0] + bias[u0];
            const float zi1 = zr[u1] + bias[u1];
            const float zf0 = zr[512 + u0] + bias[512 + u0];
            const float zf1 = zr[512 + u1] + bias[512 + u1];
            const float zo0 = zr[1536 + u0] + bias[1536 + u0];
            const float zo1 = zr[1536 + u1] + bias[1536 + u1];
            float cv0 = sigm(zf0) * cenc[(size_t)ur * 512 + u0] + sigm(zi0) * (e0 * inv);
            float cv1 = sigm(zf1) * cenc[(size_t)ur * 512 + u1] + sigm(zi1) * (e1 * inv);
            cenc[(size_t)ur * 512 + u0] = cv0;
            cenc[(size_t)ur * 512 + u1] = cv1;
            const float mx2 = blk_max(fmaxf(cv0, cv1), red);
            float ec0 = __expf(cv0 - mx2), ec1 = __expf(cv1 - mx2);
            const float inv2 = 1.0f / blk_sum(ec0 + ec1, red);
            hout[(size_t)ur * 512 + u0] = sigm(zo0) * ec0 * inv2;
            hout[(size_t)ur * 512 + u1] = sigm(zo1) * ec1 * inv2;
        }
        __syncthreads();
        if (tid == 0) { __threadfence(); add_rel(hc + t); }
    }
}

// ---------------------------------------------------------------------------
// Decoder: 256 blocks, pipelines p = mt*2 + dir (dir = nt>>4). K=256.
// Updater: each of the 16 col-blocks of a pipeline updates 2 rows.
// ---------------------------------------------------------------------------
__global__ __launch_bounds__(256) void dec_persistent(
    const float* __restrict__ xw, const float* __restrict__ Uf,
    const float* __restrict__ Ub, float* __restrict__ hf,
    float* __restrict__ hb, float* __restrict__ cf, float* __restrict__ cb,
    float* __restrict__ z, float* __restrict__ hseq, int* __restrict__ fl)
{
    const int bid = blockIdx.x;
    const int nt = bid & 31, mt = bid >> 5;
    const int dir = nt >> 4;
    const int p = mt * 2 + dir;
    const int tid = threadIdx.x;
    const int tr = tid >> 4, tc = tid & 15;
    const int r0 = mt * 32 + tr, r1 = r0 + 16;
    const int c0 = nt * 64 + tc * 4;            // z col (dir folded in)
    const int cl = (nt & 15) * 64 + tc * 4;     // B col
    const float* Bw = dir ? Ub : Uf;
    float* hstate = dir ? hb : hf;
    float* cstate = dir ? cb : cf;
    int* zc = fl + 4096 + p * 64;
    int* hc = fl + 5120 + p * 64;

    for (int s = 0; s < 64; ++s) {
        if (s > 0) {
            if (tid == 0) { while (ld_acq(hc + (s - 1)) < 16) __builtin_amdgcn_s_sleep(1); }
            __syncthreads();
        }
        float4 o0 = {0, 0, 0, 0}, o1 = {0, 0, 0, 0};
        const float* hp = hstate + (size_t)((s + 1) & 1) * 65536;
        gemm_slab(hp + (size_t)r0 * 256, hp + (size_t)r1 * 256, Bw + cl, 256, 1024, o0, o1);
        *(float4*)(z + (size_t)r0 * 2048 + c0) = o0;
        *(float4*)(z + (size_t)r1 * 2048 + c0) = o1;
        __syncthreads();
        if (tid == 0) { __threadfence(); add_rel(zc + s); }

        // ---- elementwise update: 2 rows per block ----
        if (tid == 0) { while (ld_acq(zc + s) < 16) __builtin_amdgcn_s_sleep(1); }
        __syncthreads();
        {
            float* hout = hstate + (size_t)(s & 1) * 65536;
            const int u = tid;
            const int col = dir * 1024 + u;
            const int tt = dir ? (63 - s) : s;
            #pragma unroll
            for (int rr = 0; rr < 2; ++rr) {
                const int r = mt * 32 + (nt & 15) * 2 + rr;
                const size_t base = (size_t)r * 2048 + col;
                const float zi = z[base]       + xw[base];
                const float zf = z[base + 256] + xw[base + 256];
                const float zg = z[base + 512] + xw[base + 512];
                const float zo = z[base + 768] + xw[base + 768];
                const size_t ci = (size_t)r * 256 + u;
                const float cv = sigm(zf) * cstate[ci] + sigm(zi) * tanhf(zg);
                cstate[ci] = cv;
                const float hv = sigm(zo) * tanhf(cv);
                hout[ci] = hv;
                hseq[((size_t)r * 64 + tt) * 512 + dir * 256 + u] = hv;
            }
        }
        __syncthreads();
        if (tid == 0) { __threadfence(); add_rel(hc + s); }
    }
}

// ---------------------------------------------------------------------------
// dec input projection: zpart[ks][256][2048] = hEnc[256x512-slice] @ [dfK|dbK]
// BM=32, BN=64, BK=16, 128 threads, K split 4x128.
// ---------------------------------------------------------------------------
__global__ __launch_bounds__(128) void gemm_xwproj(
    const float* __restrict__ A, const float* __restrict__ Bf,
    const float* __restrict__ Bb, float* __restrict__ zpart)
{
    const int n0 = blockIdx.x * 64;
    const int m0 = blockIdx.y * 32;
    const int kbeg = blockIdx.z * 128;

    __shared__ __align__(16) float As[16][36];
    __shared__ __align__(16) float Bs[16][68];

    const int tid = threadIdx.x;
    const int am = tid & 31, akq = tid >> 5;
    const int bc4 = tid & 15, bkr = tid >> 4;
    const int cr = tid >> 4, cc = tid & 15;

    float acc[4][4] = {};
    const float* bp = (n0 < 1024) ? Bf : Bb;
    const int nn = (n0 < 1024) ? n0 : (n0 - 1024);

    for (int kb = kbeg; kb < kbeg + 128; kb += 16) {
        {
            const int kg = kb + akq * 4;
            const float4 av = *(const float4*)(A + (size_t)(m0 + am) * 512 + kg);
            As[akq * 4 + 0][am] = av.x;
            As[akq * 4 + 1][am] = av.y;
            As[akq * 4 + 2][am] = av.z;
            As[akq * 4 + 3][am] = av.w;
        }
        #pragma unroll
        for (int pp = 0; pp < 2; ++pp) {
            const int kg = kb + pp * 8 + bkr;
            *(float4*)&Bs[pp * 8 + bkr][bc4 * 4] =
                *(const float4*)(bp + (size_t)kg * 1024 + nn + bc4 * 4);
        }
        __syncthreads();
        #pragma unroll
        for (int kk = 0; kk < 16; ++kk) {
            const float4 av = *(const float4*)&As[kk][cr * 4];
            const float4 bv = *(const float4*)&Bs[kk][cc * 4];
            const float aa[4] = {av.x, av.y, av.z, av.w};
            const float bb[4] = {bv.x, bv.y, bv.z, bv.w};
            #pragma unroll
            for (int i = 0; i < 4; ++i)
                #pragma unroll
                for (int j = 0; j < 4; ++j)
                    acc[i][j] = fmaf(aa[i], bb[j], acc[i][j]);
        }
        __syncthreads();
    }

    float* zp = zpart + (size_t)blockIdx.z * 524288;
    #pragma unroll
    for (int i = 0; i < 4; ++i) {
        float4 v = {acc[i][0], acc[i][1], acc[i][2], acc[i][3]};
        *(float4*)(zp + (size_t)(m0 + cr * 4 + i) * 2048 + n0 + cc * 4) = v;
    }
}

__global__ __launch_bounds__(256) void xw_reduce(
    const float* __restrict__ zpart, const float* __restrict__ bf,
    const float* __restrict__ bb, float* __restrict__ xw)
{
    const int i = blockIdx.x * 256 + threadIdx.x;  // 524288 total
    const int n = i & 2047;
    const float bias = (n < 1024) ? bf[n] : bb[n - 1024];
    xw[i] = zpart[i] + zpart[i + 524288] + zpart[i + 2 * 524288] + zpart[i + 3 * 524288] + bias;
}

__global__ __launch_bounds__(256) void dense_kernel(
    const float* __restrict__ hseq, const float* __restrict__ Dk,
    const float* __restrict__ Db, float* __restrict__ out)
{
    __shared__ float dk[8192];  // 512 x 16
    for (int i = threadIdx.x; i < 8192; i += 256) dk[i] = Dk[i];
    __syncthreads();
    const int f = threadIdx.x & 15;
    const int bt = blockIdx.x * 16 + (threadIdx.x >> 4);
    const float* hs = hseq + (size_t)bt * 512;
    float acc = Db[f];
    #pragma unroll 4
    for (int k = 0; k < 512; k += 4) {
        const float4 hv = *(const float4*)(hs + k);
        acc += hv.x * dk[(k + 0) * 16 + f] + hv.y * dk[(k + 1) * 16 + f]
             + hv.z * dk[(k + 2) * 16 + f] + hv.w * dk[(k + 3) * 16 + f];
    }
    out[(size_t)bt * 16 + f] = acc;
}

__global__ __launch_bounds__(256) void init_ws(float* __restrict__ ws)
{
    const int idx = blockIdx.x * 256 + threadIdx.x;
    const float4 zz = {0.f, 0.f, 0.f, 0.f};
    if (idx < 196608) ((float4*)ws)[idx] = zz;                       // states
    else ((float4*)(ws + OFS_FLAGS))[idx - 196608] = zz;             // flags
}

// ---------------------------------------------------------------------------
extern "C" void kernel_launch(void* const* d_in, const int* in_sizes, int n_in,
                              void* d_out, int out_size, void* d_ws, size_t ws_size,
                              hipStream_t stream)
{
    const float* x    = (const float*)d_in[0];
    const float* encW = (const float*)d_in[1];
    const float* encU = (const float*)d_in[2];
    const float* encB = (const float*)d_in[3];
    const float* dfK  = (const float*)d_in[4];
    const float* dfU  = (const float*)d_in[5];
    const float* dfB  = (const float*)d_in[6];
    const float* dbK  = (const float*)d_in[7];
    const float* dbU  = (const float*)d_in[8];
    const float* dbB  = (const float*)d_in[9];
    const float* dK   = (const float*)d_in[10];
    const float* dB   = (const float*)d_in[11];

    if (ws_size < WS_FLOATS * sizeof(float)) return;

    float* ws    = (float*)d_ws;
    float* henc  = ws + OFS_HENC;
    float* cenc  = ws + OFS_CENC;
    float* hf    = ws + OFS_HF;
    float* hb    = ws + OFS_HB;
    float* cf    = ws + OFS_CF;
    float* cb    = ws + OFS_CB;
    float* zbuf  = ws + OFS_Z;
    float* xw    = ws + OFS_XW;
    float* hseq  = ws + OFS_HSEQ;
    float* zpart = ws + OFS_HSEQ;               // alias: used before hseq written
    int*   fl    = (int*)(ws + OFS_FLAGS);

    init_ws<<<776, 256, 0, stream>>>(ws);

    enc_persistent<<<256, 256, 0, stream>>>(x, encW, encU, encB, henc, cenc, zbuf, fl);

    // decoder input projection from final encoder h (buffer parity 255&1 = 1)
    gemm_xwproj<<<dim3(32, 8, 4), 128, 0, stream>>>(henc + 131072, dfK, dbK, zpart);
    xw_reduce<<<2048, 256, 0, stream>>>(zpart, dfB, dbB, xw);

    dec_persistent<<<256, 256, 0, stream>>>(xw, dfU, dbU, hf, hb, cf, cb, zbuf, hseq, fl);

    dense_kernel<<<1024, 256, 0, stream>>>(hseq, dK, dB, (float*)d_out);
}

// Round 3
// 8908.291 us; speedup vs baseline: 1.9359x; 1.9359x over previous
//
#include <hip/hip_runtime.h>

// ---------------------------------------------------------------------------
// One-launch-per-step fused LSTM. Each block owns 32 rows x 64 z-cols.
// Phase 1: redundantly compute h_{t-1},c_{t-1} for its 32 rows from z_{t-1}
//          (softmax couples only within a row -> block-local). h -> LDS.
// Phase 2: z_t tile = [x_t | h] @ [W;U] cols, B double-buffered through LDS.
// Cross-launch handoff via global z/c (kernel boundary = cheap device barrier).
// ---------------------------------------------------------------------------

#define OFS_ZENC   0u          // [2][256][2048]
#define OFS_CENC   1048576u    // [2][256][512]
#define OFS_XWD    1310720u    // [256][2048]
#define OFS_ZDEC   1835008u    // [2][256][2048]
#define OFS_HENC   2359296u    // [256][512]  (aliases zdec parity-1; dead before s=1 write)
#define OFS_CDEC   2883584u    // [2][2][256][256]
#define OFS_HSEQ   3145728u    // [256][64][512]
#define WS_FLOATS  11534336u

__device__ __forceinline__ float frcp(float x) { return __builtin_amdgcn_rcpf(x); }
__device__ __forceinline__ float sigm1(float x) { return frcp(1.0f + __expf(-x)); }
__device__ __forceinline__ float tanh1(float x) { return 2.0f * frcp(1.0f + __expf(-2.0f * x)) - 1.0f; }

__device__ __forceinline__ float4 ld4(const float* p) { return *(const float4*)p; }
__device__ __forceinline__ void st4(float* p, float4 v) { *(float4*)p = v; }
__device__ __forceinline__ float4 add4(float4 a, float4 b) {
    return float4{a.x + b.x, a.y + b.y, a.z + b.z, a.w + b.w};
}
__device__ __forceinline__ float4 exp4(float4 a) {
    return float4{__expf(a.x), __expf(a.y), __expf(a.z), __expf(a.w)};
}
__device__ __forceinline__ float hsum4(float4 a) { return (a.x + a.y) + (a.z + a.w); }

// ---------------------------------------------------------------------------
// Encoder step. grid 256 blocks (mt=bid>>5 rows, nt=bid&31 cols), 256 threads.
// dynamic LDS: As[576*33] (A in [k][r], +1-pad) then Bs[2][32*64].
// ---------------------------------------------------------------------------
#define AS(k, r) lds[(k) * 33 + (r)]
#define BS_OFF 19008

__global__ __launch_bounds__(256) void enc_step(
    const float* __restrict__ x,     // [256][256][64]
    const float* __restrict__ W,     // [64][2048]
    const float* __restrict__ U,     // [512][2048]
    const float* __restrict__ bias,  // [2048]
    float* __restrict__ zenc,        // [2][256][2048]
    float* __restrict__ cenc,        // [2][256][512]
    float* __restrict__ henc,        // [256][512]
    int t)
{
    extern __shared__ float lds[];
    const int bid = blockIdx.x;
    const int nt = bid & 31, mt = bid >> 5;
    const int tid = threadIdx.x;

    // ---- x tile prefetch to registers (rows 32 x k 64) ----
    float4 xr0{0,0,0,0}, xr1{0,0,0,0};
    if (t < 256) {
        const float* xp = x + ((size_t)(mt * 32 + (tid >> 3)) * 256 + t) * 64 + (tid & 7) * 8;
        xr0 = ld4(xp); xr1 = ld4(xp + 4);
    }

    // ---- phase 1: gate update for this block's 32 rows (t >= 1) ----
    if (t >= 1) {
        const int r = tid >> 3, ug = tid & 7;
        const int grow = mt * 32 + r;
        const float* zr = zenc + (size_t)((t - 1) & 1) * 524288 + (size_t)grow * 2048;
        const float* cp = cenc + (size_t)(t & 1) * 131072 + (size_t)grow * 512;
        float*       cn = cenc + (size_t)((t + 1) & 1) * 131072 + (size_t)grow * 512;
        const int ub = ug * 8;

        float4 ea[8], eb[8];
        float sumg = 0.f;
        #pragma unroll
        for (int m = 0; m < 8; ++m) {
            const int idx = m * 64 + ub;
            float4 g0 = add4(ld4(zr + 1024 + idx),     ld4(bias + 1024 + idx));
            float4 g1 = add4(ld4(zr + 1024 + idx + 4), ld4(bias + 1024 + idx + 4));
            g0 = exp4(g0); g1 = exp4(g1);
            ea[m] = g0; eb[m] = g1;
            sumg += hsum4(g0) + hsum4(g1);
        }
        sumg += __shfl_xor(sumg, 1); sumg += __shfl_xor(sumg, 2); sumg += __shfl_xor(sumg, 4);
        const float ginv = frcp(sumg);

        float sumc = 0.f;
        #pragma unroll
        for (int m = 0; m < 8; ++m) {
            const int idx = m * 64 + ub;
            float4 zi0 = add4(ld4(zr + idx),           ld4(bias + idx));
            float4 zi1 = add4(ld4(zr + idx + 4),       ld4(bias + idx + 4));
            float4 zf0 = add4(ld4(zr + 512 + idx),     ld4(bias + 512 + idx));
            float4 zf1 = add4(ld4(zr + 512 + idx + 4), ld4(bias + 512 + idx + 4));
            float4 c0{0,0,0,0}, c1{0,0,0,0};
            if (t >= 2) { c0 = ld4(cp + idx); c1 = ld4(cp + idx + 4); }
            float4 cv0, cv1;
            cv0.x = sigm1(zf0.x) * c0.x + sigm1(zi0.x) * (ea[m].x * ginv);
            cv0.y = sigm1(zf0.y) * c0.y + sigm1(zi0.y) * (ea[m].y * ginv);
            cv0.z = sigm1(zf0.z) * c0.z + sigm1(zi0.z) * (ea[m].z * ginv);
            cv0.w = sigm1(zf0.w) * c0.w + sigm1(zi0.w) * (ea[m].w * ginv);
            cv1.x = sigm1(zf1.x) * c1.x + sigm1(zi1.x) * (eb[m].x * ginv);
            cv1.y = sigm1(zf1.y) * c1.y + sigm1(zi1.y) * (eb[m].y * ginv);
            cv1.z = sigm1(zf1.z) * c1.z + sigm1(zi1.z) * (eb[m].z * ginv);
            cv1.w = sigm1(zf1.w) * c1.w + sigm1(zi1.w) * (eb[m].w * ginv);
            st4(cn + idx, cv0); st4(cn + idx + 4, cv1);
            float4 ec0 = exp4(cv0), ec1 = exp4(cv1);
            ea[m] = ec0; eb[m] = ec1;
            sumc += hsum4(ec0) + hsum4(ec1);
        }
        sumc += __shfl_xor(sumc, 1); sumc += __shfl_xor(sumc, 2); sumc += __shfl_xor(sumc, 4);
        const float cinv = frcp(sumc);

        #pragma unroll
        for (int m = 0; m < 8; ++m) {
            const int idx = m * 64 + ub;
            float4 zo0 = add4(ld4(zr + 1536 + idx),     ld4(bias + 1536 + idx));
            float4 zo1 = add4(ld4(zr + 1536 + idx + 4), ld4(bias + 1536 + idx + 4));
            float4 h0, h1;
            h0.x = sigm1(zo0.x) * ea[m].x * cinv; h0.y = sigm1(zo0.y) * ea[m].y * cinv;
            h0.z = sigm1(zo0.z) * ea[m].z * cinv; h0.w = sigm1(zo0.w) * ea[m].w * cinv;
            h1.x = sigm1(zo1.x) * eb[m].x * cinv; h1.y = sigm1(zo1.y) * eb[m].y * cinv;
            h1.z = sigm1(zo1.z) * eb[m].z * cinv; h1.w = sigm1(zo1.w) * eb[m].w * cinv;
            AS(64 + idx + 0, r) = h0.x; AS(64 + idx + 1, r) = h0.y;
            AS(64 + idx + 2, r) = h0.z; AS(64 + idx + 3, r) = h0.w;
            AS(64 + idx + 4, r) = h1.x; AS(64 + idx + 5, r) = h1.y;
            AS(64 + idx + 6, r) = h1.z; AS(64 + idx + 7, r) = h1.w;
            if (t == 256 && nt == 0) {
                st4(henc + (size_t)grow * 512 + idx, h0);
                st4(henc + (size_t)grow * 512 + idx + 4, h1);
            }
        }
    }

    // ---- stage x tile into As[k<64] ----
    if (t < 256) {
        const int row = tid >> 3, kq = (tid & 7) * 8;
        AS(kq + 0, row) = xr0.x; AS(kq + 1, row) = xr0.y;
        AS(kq + 2, row) = xr0.z; AS(kq + 3, row) = xr0.w;
        AS(kq + 4, row) = xr1.x; AS(kq + 5, row) = xr1.y;
        AS(kq + 6, row) = xr1.z; AS(kq + 7, row) = xr1.w;
    }
    __syncthreads();

    // ---- phase 2: GEMM z_t tile ----
    if (t < 256) {
        const int tr = tid >> 4, tc = tid & 15;
        const int brow = tid >> 3, bcg = (tid & 7) * 8;
        const int nch = (t > 0) ? 18 : 2;
        float4 a0{0,0,0,0}, a1{0,0,0,0};

        const float* bp0 = W + (size_t)brow * 2048 + nt * 64 + bcg;
        float4 pb0 = ld4(bp0), pb1 = ld4(bp0 + 4);

        for (int ch = 0; ch < nch; ++ch) {
            float* bs = lds + BS_OFF + (ch & 1) * 2048;
            st4(bs + brow * 64 + bcg, pb0);
            st4(bs + brow * 64 + bcg + 4, pb1);
            __syncthreads();
            if (ch + 1 < nch) {
                const int k = (ch + 1) * 32 + brow;
                const float* bp = (k < 64) ? (W + (size_t)k * 2048 + nt * 64 + bcg)
                                           : (U + (size_t)(k - 64) * 2048 + nt * 64 + bcg);
                pb0 = ld4(bp); pb1 = ld4(bp + 4);
            }
            const int kb = ch * 32;
            #pragma unroll
            for (int kk = 0; kk < 32; ++kk) {
                const float av0 = AS(kb + kk, tr);
                const float av1 = AS(kb + kk, tr + 16);
                const float4 b = ld4(bs + kk * 64 + tc * 4);
                a0.x = fmaf(av0, b.x, a0.x); a0.y = fmaf(av0, b.y, a0.y);
                a0.z = fmaf(av0, b.z, a0.z); a0.w = fmaf(av0, b.w, a0.w);
                a1.x = fmaf(av1, b.x, a1.x); a1.y = fmaf(av1, b.y, a1.y);
                a1.z = fmaf(av1, b.z, a1.z); a1.w = fmaf(av1, b.w, a1.w);
            }
            __syncthreads();
        }
        float* zo = zenc + (size_t)(t & 1) * 524288 + (size_t)(mt * 32) * 2048 + (size_t)nt * 64;
        st4(zo + tr * 2048 + tc * 4, a0);
        st4(zo + (tr + 16) * 2048 + tc * 4, a1);
    }
}

// ---------------------------------------------------------------------------
// Decoder step. grid 256 (mt=bid>>5, nt=bid&31, dir=nt>>4), 256 threads.
// ---------------------------------------------------------------------------
__global__ __launch_bounds__(256) void dec_step(
    const float* __restrict__ Uf,    // [256][1024]
    const float* __restrict__ Ub,
    const float* __restrict__ xwd,   // [256][2048] bias folded
    float* __restrict__ zdec,        // [2][256][2048]
    float* __restrict__ cdec,        // [2][2][256][256]
    float* __restrict__ hseq,        // [256][64][512]
    int s)
{
    __shared__ float Asd[256 * 33];
    __shared__ float Bsd[2][2048];
    const int bid = blockIdx.x;
    const int nt = bid & 31, mt = bid >> 5;
    const int dir = nt >> 4;
    const int tid = threadIdx.x;

    // ---- phase 1: h_{s-1}, c_{s-1} for 32 rows (elementwise, tanh) ----
    {
        const int r = tid >> 3, ug = tid & 7;
        const int grow = mt * 32 + r;
        const float* zr = zdec + (size_t)((s - 1) & 1) * 524288 + (size_t)grow * 2048 + dir * 1024;
        const float* xp = xwd + (size_t)grow * 2048 + dir * 1024;
        const float* cp = cdec + (size_t)(s & 1) * 131072 + dir * 65536 + (size_t)grow * 256;
        float*       cn = cdec + (size_t)((s + 1) & 1) * 131072 + dir * 65536 + (size_t)grow * 256;
        const int tt = dir ? (64 - s) : (s - 1);
        #pragma unroll
        for (int m = 0; m < 8; ++m) {
            const int idx = m * 32 + ug * 4;
            float4 zi = ld4(xp + idx);
            float4 zf = ld4(xp + 256 + idx);
            float4 zg = ld4(xp + 512 + idx);
            float4 zo = ld4(xp + 768 + idx);
            float4 cv0{0,0,0,0};
            if (s > 1) {
                zi = add4(zi, ld4(zr + idx));
                zf = add4(zf, ld4(zr + 256 + idx));
                zg = add4(zg, ld4(zr + 512 + idx));
                zo = add4(zo, ld4(zr + 768 + idx));
                cv0 = ld4(cp + idx);
            }
            float4 cv, h;
            cv.x = sigm1(zf.x) * cv0.x + sigm1(zi.x) * tanh1(zg.x);
            cv.y = sigm1(zf.y) * cv0.y + sigm1(zi.y) * tanh1(zg.y);
            cv.z = sigm1(zf.z) * cv0.z + sigm1(zi.z) * tanh1(zg.z);
            cv.w = sigm1(zf.w) * cv0.w + sigm1(zi.w) * tanh1(zg.w);
            st4(cn + idx, cv);
            h.x = sigm1(zo.x) * tanh1(cv.x); h.y = sigm1(zo.y) * tanh1(cv.y);
            h.z = sigm1(zo.z) * tanh1(cv.z); h.w = sigm1(zo.w) * tanh1(cv.w);
            Asd[(idx + 0) * 33 + r] = h.x; Asd[(idx + 1) * 33 + r] = h.y;
            Asd[(idx + 2) * 33 + r] = h.z; Asd[(idx + 3) * 33 + r] = h.w;
            if ((nt & 15) == 0)
                st4(hseq + ((size_t)grow * 64 + tt) * 512 + dir * 256 + idx, h);
        }
    }
    __syncthreads();

    // ---- phase 2: z_s tile = h @ Udir ----
    if (s < 64) {
        const int tr = tid >> 4, tc = tid & 15;
        const int brow = tid >> 3, bcg = (tid & 7) * 8;
        const int cl = (nt & 15) * 64;
        const float* Ud = dir ? Ub : Uf;
        float4 a0{0,0,0,0}, a1{0,0,0,0};

        const float* bp0 = Ud + (size_t)brow * 1024 + cl + bcg;
        float4 pb0 = ld4(bp0), pb1 = ld4(bp0 + 4);

        for (int ch = 0; ch < 8; ++ch) {
            float* bs = Bsd[ch & 1];
            st4(bs + brow * 64 + bcg, pb0);
            st4(bs + brow * 64 + bcg + 4, pb1);
            __syncthreads();
            if (ch + 1 < 8) {
                const int k = (ch + 1) * 32 + brow;
                const float* bp = Ud + (size_t)k * 1024 + cl + bcg;
                pb0 = ld4(bp); pb1 = ld4(bp + 4);
            }
            const int kb = ch * 32;
            #pragma unroll
            for (int kk = 0; kk < 32; ++kk) {
                const float av0 = Asd[(kb + kk) * 33 + tr];
                const float av1 = Asd[(kb + kk) * 33 + tr + 16];
                const float4 b = ld4(bs + kk * 64 + tc * 4);
                a0.x = fmaf(av0, b.x, a0.x); a0.y = fmaf(av0, b.y, a0.y);
                a0.z = fmaf(av0, b.z, a0.z); a0.w = fmaf(av0, b.w, a0.w);
                a1.x = fmaf(av1, b.x, a1.x); a1.y = fmaf(av1, b.y, a1.y);
                a1.z = fmaf(av1, b.z, a1.z); a1.w = fmaf(av1, b.w, a1.w);
            }
            __syncthreads();
        }
        float* zo = zdec + (size_t)(s & 1) * 524288 + (size_t)(mt * 32) * 2048 + (size_t)nt * 64;
        st4(zo + tr * 2048 + tc * 4, a0);
        st4(zo + (tr + 16) * 2048 + tc * 4, a1);
    }
}

// ---------------------------------------------------------------------------
// Decoder input projection: xwd = henc @ [dfK|dbK] + bias. K=512.
// ---------------------------------------------------------------------------
__global__ __launch_bounds__(128) void dec_proj(
    const float* __restrict__ A, const float* __restrict__ Bf,
    const float* __restrict__ Bb, const float* __restrict__ bf,
    const float* __restrict__ bb, float* __restrict__ xwd)
{
    const int n0 = blockIdx.x * 64;
    const int m0 = blockIdx.y * 32;
    __shared__ __align__(16) float As[16][36];
    __shared__ __align__(16) float Bs[16][68];
    const int tid = threadIdx.x;
    const int am = tid & 31, akq = tid >> 5;
    const int bc4 = tid & 15, bkr = tid >> 4;
    const int cr = tid >> 4, cc = tid & 15;

    float acc[4][4] = {};
    const float* bp = (n0 < 1024) ? Bf : Bb;
    const float* bia = (n0 < 1024) ? bf : bb;
    const int nn = (n0 < 1024) ? n0 : (n0 - 1024);

    for (int kb = 0; kb < 512; kb += 16) {
        {
            const int kg = kb + akq * 4;
            const float4 av = ld4(A + (size_t)(m0 + am) * 512 + kg);
            As[akq * 4 + 0][am] = av.x; As[akq * 4 + 1][am] = av.y;
            As[akq * 4 + 2][am] = av.z; As[akq * 4 + 3][am] = av.w;
        }
        #pragma unroll
        for (int pp = 0; pp < 2; ++pp) {
            const int kg = kb + pp * 8 + bkr;
            *(float4*)&Bs[pp * 8 + bkr][bc4 * 4] = ld4(bp + (size_t)kg * 1024 + nn + bc4 * 4);
        }
        __syncthreads();
        #pragma unroll
        for (int kk = 0; kk < 16; ++kk) {
            const float4 av = *(const float4*)&As[kk][cr * 4];
            const float4 bv = *(const float4*)&Bs[kk][cc * 4];
            const float aa[4] = {av.x, av.y, av.z, av.w};
            const float bbv[4] = {bv.x, bv.y, bv.z, bv.w};
            #pragma unroll
            for (int i = 0; i < 4; ++i)
                #pragma unroll
                for (int j = 0; j < 4; ++j)
                    acc[i][j] = fmaf(aa[i], bbv[j], acc[i][j]);
        }
        __syncthreads();
    }
    #pragma unroll
    for (int i = 0; i < 4; ++i) {
        const int col = nn + cc * 4;
        float4 v = {acc[i][0] + bia[col], acc[i][1] + bia[col + 1],
                    acc[i][2] + bia[col + 2], acc[i][3] + bia[col + 3]};
        st4(xwd + (size_t)(m0 + cr * 4 + i) * 2048 + n0 + cc * 4, v);
    }
}

// ---------------------------------------------------------------------------
__global__ __launch_bounds__(256) void dense_kernel(
    const float* __restrict__ hseq, const float* __restrict__ Dk,
    const float* __restrict__ Db, float* __restrict__ out)
{
    __shared__ float dk[8192];
    for (int i = threadIdx.x; i < 8192; i += 256) dk[i] = Dk[i];
    __syncthreads();
    const int f = threadIdx.x & 15;
    const int bt = blockIdx.x * 16 + (threadIdx.x >> 4);
    const float* hs = hseq + (size_t)bt * 512;
    float acc = Db[f];
    #pragma unroll 4
    for (int k = 0; k < 512; k += 4) {
        const float4 hv = ld4(hs + k);
        acc += hv.x * dk[(k + 0) * 16 + f] + hv.y * dk[(k + 1) * 16 + f]
             + hv.z * dk[(k + 2) * 16 + f] + hv.w * dk[(k + 3) * 16 + f];
    }
    out[(size_t)bt * 16 + f] = acc;
}

// ---------------------------------------------------------------------------
extern "C" void kernel_launch(void* const* d_in, const int* in_sizes, int n_in,
                              void* d_out, int out_size, void* d_ws, size_t ws_size,
                              hipStream_t stream)
{
    const float* x    = (const float*)d_in[0];
    const float* encW = (const float*)d_in[1];
    const float* encU = (const float*)d_in[2];
    const float* encB = (const float*)d_in[3];
    const float* dfK  = (const float*)d_in[4];
    const float* dfU  = (const float*)d_in[5];
    const float* dfB  = (const float*)d_in[6];
    const float* dbK  = (const float*)d_in[7];
    const float* dbU  = (const float*)d_in[8];
    const float* dbB  = (const float*)d_in[9];
    const float* dK   = (const float*)d_in[10];
    const float* dB   = (const float*)d_in[11];

    if (ws_size < WS_FLOATS * sizeof(float)) return;

    float* ws   = (float*)d_ws;
    float* zenc = ws + OFS_ZENC;
    float* cenc = ws + OFS_CENC;
    float* xwd  = ws + OFS_XWD;
    float* zdec = ws + OFS_ZDEC;
    float* henc = ws + OFS_HENC;
    float* cdec = ws + OFS_CDEC;
    float* hseq = ws + OFS_HSEQ;

    const int ENC_LDS = (576 * 33 + 2 * 2048) * 4;  // 92416 B
    hipFuncSetAttribute(reinterpret_cast<const void*>(enc_step),
                        hipFuncAttributeMaxDynamicSharedMemorySize, ENC_LDS);

    for (int t = 0; t <= 256; ++t)
        enc_step<<<256, 256, ENC_LDS, stream>>>(x, encW, encU, encB, zenc, cenc, henc, t);

    dec_proj<<<dim3(32, 8), 128, 0, stream>>>(henc, dfK, dbK, dfB, dbB, xwd);

    for (int s = 1; s <= 64; ++s)
        dec_step<<<256, 256, 0, stream>>>(dfU, dbU, xwd, zdec, cdec, hseq, s);

    dense_kernel<<<1024, 256, 0, stream>>>(hseq, dK, dB, (float*)d_out);
}

// Round 4
// 5981.174 us; speedup vs baseline: 2.8833x; 1.4894x over previous
//
#include <hip/hip_runtime.h>

// ---------------------------------------------------------------------------
// Encoder: split-bf16 MFMA (32x32x16), fragment-packed weights, 2 launches/step:
//   enc_upd  : 256 blocks x 64 thr, 1 row/block: z_t -> softmax gates -> c,h;
//              writes h as A-fragments (hi/lo bf16) + henc fp32.
//   enc_gemm : 256 blocks x 128 thr (2 waves), z_{t+1} tile 32 rows x 64 cols;
//              A-frags (x: cvt on the fly, h: packed global), B-frags packed
//              global, 3 MFMAs per k-step (hi*hi + hi*lo + lo*hi).
// Decoder: unchanged from R3 (fp32, fused step kernel).
// Coherence between launches via kernel boundaries (same stream).
// ---------------------------------------------------------------------------

typedef __attribute__((ext_vector_type(8)))  short bf16x8;
typedef __attribute__((ext_vector_type(16))) float f32x16;

#define MFMA(a, b, c) __builtin_amdgcn_mfma_f32_32x32x16_bf16((a), (b), (c), 0, 0, 0)

// ws layout (float offsets). Region [0, 8388608) = bfrag (enc) ALIASED with
// hseq (dec) — bfrag is dead once the encoder finishes.
#define OFS_ZENC  8388608u    // [256][2048]
#define OFS_CENC  8912896u    // [256][512]
#define OFS_HENC  9043968u    // [256][512]
#define OFS_HFRAG 9175040u    // hi/lo shorts: 2 x 131072
#define OFS_XWD   9306112u    // [256][2048]
#define OFS_ZDEC  9830400u    // [2][256][2048]
#define OFS_CDEC  10878976u   // [2][2][256][256]
#define WS_FLOATS 11141120u

__device__ __forceinline__ float frcp(float x) { return __builtin_amdgcn_rcpf(x); }
__device__ __forceinline__ float sigm(float x) { return frcp(1.0f + __expf(-x)); }
__device__ __forceinline__ float4 ld4(const float* p) { return *(const float4*)p; }
__device__ __forceinline__ void st4(float* p, float4 v) { *(float4*)p = v; }
__device__ __forceinline__ float4 add4(float4 a, float4 b) {
    return float4{a.x + b.x, a.y + b.y, a.z + b.z, a.w + b.w};
}

__device__ __forceinline__ short f2bf(float f) {      // fp32 -> bf16 RNE
    unsigned u = __float_as_uint(f);
    u = u + 0x7FFFu + ((u >> 16) & 1u);
    return (short)(u >> 16);
}
__device__ __forceinline__ float bf2f(short s) {
    return __uint_as_float(((unsigned)(unsigned short)s) << 16);
}

// ---------------------------------------------------------------------------
// Pack W(64x2048),U(512x2048) into B-fragment order for 32x32x16:
// lane l holds B[k = ks*16 + (l>>5)*8 + j][col = ct*32 + (l&31)], j=0..7.
// Storage: frag[ct][ks][lane][8] shorts, hi and lo arrays.
// ---------------------------------------------------------------------------
__global__ __launch_bounds__(64) void bfrag_prep(
    const float* __restrict__ W, const float* __restrict__ U,
    short* __restrict__ bh, short* __restrict__ bl)
{
    const int ks = blockIdx.x;          // 0..35
    const int ct = blockIdx.y;          // 0..63
    const int l  = threadIdx.x;         // 0..63
    const int col = ct * 32 + (l & 31);
    const int kbase = ks * 16 + (l >> 5) * 8;
    bf16x8 h8, l8;
    #pragma unroll
    for (int j = 0; j < 8; ++j) {
        const int k = kbase + j;
        const float v = (k < 64) ? W[(size_t)k * 2048 + col]
                                 : U[(size_t)(k - 64) * 2048 + col];
        const short hi = f2bf(v);
        h8[j] = hi;
        l8[j] = f2bf(v - bf2f(hi));
    }
    const size_t off = ((size_t)(ct * 36 + ks) * 64 + l) * 8;
    *(bf16x8*)(bh + off) = h8;
    *(bf16x8*)(bl + off) = l8;
}

// ---------------------------------------------------------------------------
// enc_upd: one block per batch row. z_t -> gates (softmax on g and on c) ->
// c (in place), h -> henc fp32 + hfrag (A-fragment order, hi/lo bf16).
// A-frag mapping: lane = ((u>>3)&1)*32 + (row&31), ks = u>>4, j = u&7.
// ---------------------------------------------------------------------------
__global__ __launch_bounds__(64) void enc_upd(
    const float* __restrict__ z, const float* __restrict__ bias,
    float* __restrict__ c, float* __restrict__ henc,
    short* __restrict__ hfh, short* __restrict__ hfl, int t)
{
    const int r = blockIdx.x;           // 0..255
    const int mt = r >> 5, r5 = r & 31;
    const int tid = threadIdx.x;        // 0..63
    const int u = tid * 8;
    const float* zr = z + (size_t)r * 2048;

    float g[8];
    float sg = 0.f;
    #pragma unroll
    for (int j = 0; j < 8; ++j) {
        g[j] = __expf(zr[1024 + u + j] + bias[1024 + u + j]);
        sg += g[j];
    }
    #pragma unroll
    for (int m = 1; m < 64; m <<= 1) sg += __shfl_xor(sg, m);
    const float ginv = frcp(sg);

    float ec[8];
    float sc = 0.f;
    #pragma unroll
    for (int j = 0; j < 8; ++j) {
        const float zi = zr[u + j] + bias[u + j];
        const float zf = zr[512 + u + j] + bias[512 + u + j];
        const float cold = (t > 0) ? c[(size_t)r * 512 + u + j] : 0.f;
        const float cv = sigm(zf) * cold + sigm(zi) * (g[j] * ginv);
        c[(size_t)r * 512 + u + j] = cv;
        ec[j] = __expf(cv);
        sc += ec[j];
    }
    #pragma unroll
    for (int m = 1; m < 64; m <<= 1) sc += __shfl_xor(sc, m);
    const float cinv = frcp(sc);

    float h[8];
    #pragma unroll
    for (int j = 0; j < 8; ++j) {
        const float zo = zr[1536 + u + j] + bias[1536 + u + j];
        h[j] = sigm(zo) * ec[j] * cinv;
    }
    st4(henc + (size_t)r * 512 + u,     float4{h[0], h[1], h[2], h[3]});
    st4(henc + (size_t)r * 512 + u + 4, float4{h[4], h[5], h[6], h[7]});

    bf16x8 h8, l8;
    #pragma unroll
    for (int j = 0; j < 8; ++j) {
        const short hi = f2bf(h[j]);
        h8[j] = hi;
        l8[j] = f2bf(h[j] - bf2f(hi));
    }
    const int ks = tid >> 1;                    // u>>4
    const int lane = (tid & 1) * 32 + r5;       // (u>>3)&1
    const size_t off = ((size_t)(mt * 32 + ks) * 64 + lane) * 8;
    *(bf16x8*)(hfh + off) = h8;
    *(bf16x8*)(hfl + off) = l8;
}

// ---------------------------------------------------------------------------
// enc_gemm: z_t[mt*32..+32][nt*64..+64] = [x_t | h_{t-1}] @ [W;U] via MFMA.
// 2 waves; wave w -> 32-col tile ct = nt*2 + w.
// ---------------------------------------------------------------------------
__global__ __launch_bounds__(128) void enc_gemm(
    const float* __restrict__ x, const short* __restrict__ bh,
    const short* __restrict__ bl, const short* __restrict__ hfh,
    const short* __restrict__ hfl, float* __restrict__ z, int t)
{
    const int nt = blockIdx.x;          // 0..31
    const int mt = blockIdx.y;          // 0..7
    const int w = threadIdx.x >> 6;
    const int l = threadIdx.x & 63;
    const int ct = nt * 2 + w;

    f32x16 acc;
    #pragma unroll
    for (int i = 0; i < 16; ++i) acc[i] = 0.f;

    // ---- x part: k = 0..64, A-fragments built on the fly ----
    {
        const int row = mt * 32 + (l & 31);
        const float* xp = x + ((size_t)row * 256 + t) * 64 + (l >> 5) * 8;
        #pragma unroll
        for (int ks = 0; ks < 4; ++ks) {
            float xv[8];
            const float4 xa = ld4(xp + ks * 16);
            const float4 xb = ld4(xp + ks * 16 + 4);
            xv[0] = xa.x; xv[1] = xa.y; xv[2] = xa.z; xv[3] = xa.w;
            xv[4] = xb.x; xv[5] = xb.y; xv[6] = xb.z; xv[7] = xb.w;
            bf16x8 ah, al;
            #pragma unroll
            for (int j = 0; j < 8; ++j) {
                const short hi = f2bf(xv[j]);
                ah[j] = hi;
                al[j] = f2bf(xv[j] - bf2f(hi));
            }
            const size_t boff = ((size_t)(ct * 36 + ks) * 64 + l) * 8;
            const bf16x8 bhv = *(const bf16x8*)(bh + boff);
            const bf16x8 blv = *(const bf16x8*)(bl + boff);
            acc = MFMA(ah, bhv, acc);
            acc = MFMA(ah, blv, acc);
            acc = MFMA(al, bhv, acc);
        }
    }

    // ---- h part: k = 64..576, A-fragments from hfrag ----
    if (t > 0) {
        for (int ks = 0; ks < 32; ++ks) {
            const size_t aoff = ((size_t)(mt * 32 + ks) * 64 + l) * 8;
            const size_t boff = ((size_t)(ct * 36 + 4 + ks) * 64 + l) * 8;
            const bf16x8 ah = *(const bf16x8*)(hfh + aoff);
            const bf16x8 al = *(const bf16x8*)(hfl + aoff);
            const bf16x8 bhv = *(const bf16x8*)(bh + boff);
            const bf16x8 blv = *(const bf16x8*)(bl + boff);
            acc = MFMA(ah, bhv, acc);
            acc = MFMA(ah, blv, acc);
            acc = MFMA(al, bhv, acc);
        }
    }

    // ---- store z tile (C/D layout: col=l&31, row=(i&3)+8*(i>>2)+4*(l>>5)) ----
    const int colg = ct * 32 + (l & 31);
    #pragma unroll
    for (int i = 0; i < 16; ++i) {
        const int m = (i & 3) + 8 * (i >> 2) + 4 * (l >> 5);
        z[(size_t)(mt * 32 + m) * 2048 + colg] = acc[i];
    }
}

// ---------------------------------------------------------------------------
// Decoder (unchanged from R3): fused step kernel, fp32 VALU.
// ---------------------------------------------------------------------------
__device__ __forceinline__ float tanh1(float x) {
    return 2.0f * frcp(1.0f + __expf(-2.0f * x)) - 1.0f;
}

__global__ __launch_bounds__(256) void dec_step(
    const float* __restrict__ Uf, const float* __restrict__ Ub,
    const float* __restrict__ xwd, float* __restrict__ zdec,
    float* __restrict__ cdec, float* __restrict__ hseq, int s)
{
    __shared__ float Asd[256 * 33];
    __shared__ float Bsd[2][2048];
    const int bid = blockIdx.x;
    const int nt = bid & 31, mt = bid >> 5;
    const int dir = nt >> 4;
    const int tid = threadIdx.x;

    {
        const int r = tid >> 3, ug = tid & 7;
        const int grow = mt * 32 + r;
        const float* zr = zdec + (size_t)((s - 1) & 1) * 524288 + (size_t)grow * 2048 + dir * 1024;
        const float* xp = xwd + (size_t)grow * 2048 + dir * 1024;
        const float* cp = cdec + (size_t)(s & 1) * 131072 + dir * 65536 + (size_t)grow * 256;
        float*       cn = cdec + (size_t)((s + 1) & 1) * 131072 + dir * 65536 + (size_t)grow * 256;
        const int tt = dir ? (64 - s) : (s - 1);
        #pragma unroll
        for (int m = 0; m < 8; ++m) {
            const int idx = m * 32 + ug * 4;
            float4 zi = ld4(xp + idx);
            float4 zf = ld4(xp + 256 + idx);
            float4 zg = ld4(xp + 512 + idx);
            float4 zo = ld4(xp + 768 + idx);
            float4 cv0{0, 0, 0, 0};
            if (s > 1) {
                zi = add4(zi, ld4(zr + idx));
                zf = add4(zf, ld4(zr + 256 + idx));
                zg = add4(zg, ld4(zr + 512 + idx));
                zo = add4(zo, ld4(zr + 768 + idx));
                cv0 = ld4(cp + idx);
            }
            float4 cv, h;
            cv.x = sigm(zf.x) * cv0.x + sigm(zi.x) * tanh1(zg.x);
            cv.y = sigm(zf.y) * cv0.y + sigm(zi.y) * tanh1(zg.y);
            cv.z = sigm(zf.z) * cv0.z + sigm(zi.z) * tanh1(zg.z);
            cv.w = sigm(zf.w) * cv0.w + sigm(zi.w) * tanh1(zg.w);
            st4(cn + idx, cv);
            h.x = sigm(zo.x) * tanh1(cv.x); h.y = sigm(zo.y) * tanh1(cv.y);
            h.z = sigm(zo.z) * tanh1(cv.z); h.w = sigm(zo.w) * tanh1(cv.w);
            Asd[(idx + 0) * 33 + r] = h.x; Asd[(idx + 1) * 33 + r] = h.y;
            Asd[(idx + 2) * 33 + r] = h.z; Asd[(idx + 3) * 33 + r] = h.w;
            if ((nt & 15) == 0)
                st4(hseq + ((size_t)grow * 64 + tt) * 512 + dir * 256 + idx, h);
        }
    }
    __syncthreads();

    if (s < 64) {
        const int tr = tid >> 4, tc = tid & 15;
        const int brow = tid >> 3, bcg = (tid & 7) * 8;
        const int cl = (nt & 15) * 64;
        const float* Ud = dir ? Ub : Uf;
        float4 a0{0, 0, 0, 0}, a1{0, 0, 0, 0};

        const float* bp0 = Ud + (size_t)brow * 1024 + cl + bcg;
        float4 pb0 = ld4(bp0), pb1 = ld4(bp0 + 4);

        for (int ch = 0; ch < 8; ++ch) {
            float* bs = Bsd[ch & 1];
            st4(bs + brow * 64 + bcg, pb0);
            st4(bs + brow * 64 + bcg + 4, pb1);
            __syncthreads();
            if (ch + 1 < 8) {
                const int k = (ch + 1) * 32 + brow;
                const float* bp = Ud + (size_t)k * 1024 + cl + bcg;
                pb0 = ld4(bp); pb1 = ld4(bp + 4);
            }
            const int kb = ch * 32;
            #pragma unroll
            for (int kk = 0; kk < 32; ++kk) {
                const float av0 = Asd[(kb + kk) * 33 + tr];
                const float av1 = Asd[(kb + kk) * 33 + tr + 16];
                const float4 b = ld4(bs + kk * 64 + tc * 4);
                a0.x = fmaf(av0, b.x, a0.x); a0.y = fmaf(av0, b.y, a0.y);
                a0.z = fmaf(av0, b.z, a0.z); a0.w = fmaf(av0, b.w, a0.w);
                a1.x = fmaf(av1, b.x, a1.x); a1.y = fmaf(av1, b.y, a1.y);
                a1.z = fmaf(av1, b.z, a1.z); a1.w = fmaf(av1, b.w, a1.w);
            }
            __syncthreads();
        }
        float* zo = zdec + (size_t)(s & 1) * 524288 + (size_t)(mt * 32) * 2048 + (size_t)nt * 64;
        st4(zo + tr * 2048 + tc * 4, a0);
        st4(zo + (tr + 16) * 2048 + tc * 4, a1);
    }
}

__global__ __launch_bounds__(128) void dec_proj(
    const float* __restrict__ A, const float* __restrict__ Bf,
    const float* __restrict__ Bb, const float* __restrict__ bf,
    const float* __restrict__ bb, float* __restrict__ xwd)
{
    const int n0 = blockIdx.x * 64;
    const int m0 = blockIdx.y * 32;
    __shared__ __align__(16) float As[16][36];
    __shared__ __align__(16) float Bs[16][68];
    const int tid = threadIdx.x;
    const int am = tid & 31, akq = tid >> 5;
    const int bc4 = tid & 15, bkr = tid >> 4;
    const int cr = tid >> 4, cc = tid & 15;

    float acc[4][4] = {};
    const float* bp = (n0 < 1024) ? Bf : Bb;
    const float* bia = (n0 < 1024) ? bf : bb;
    const int nn = (n0 < 1024) ? n0 : (n0 - 1024);

    for (int kb = 0; kb < 512; kb += 16) {
        {
            const int kg = kb + akq * 4;
            const float4 av = ld4(A + (size_t)(m0 + am) * 512 + kg);
            As[akq * 4 + 0][am] = av.x; As[akq * 4 + 1][am] = av.y;
            As[akq * 4 + 2][am] = av.z; As[akq * 4 + 3][am] = av.w;
        }
        #pragma unroll
        for (int pp = 0; pp < 2; ++pp) {
            const int kg = kb + pp * 8 + bkr;
            *(float4*)&Bs[pp * 8 + bkr][bc4 * 4] = ld4(bp + (size_t)kg * 1024 + nn + bc4 * 4);
        }
        __syncthreads();
        #pragma unroll
        for (int kk = 0; kk < 16; ++kk) {
            const float4 av = *(const float4*)&As[kk][cr * 4];
            const float4 bv = *(const float4*)&Bs[kk][cc * 4];
            const float aa[4] = {av.x, av.y, av.z, av.w};
            const float bbv[4] = {bv.x, bv.y, bv.z, bv.w};
            #pragma unroll
            for (int i = 0; i < 4; ++i)
                #pragma unroll
                for (int j = 0; j < 4; ++j)
                    acc[i][j] = fmaf(aa[i], bbv[j], acc[i][j]);
        }
        __syncthreads();
    }
    #pragma unroll
    for (int i = 0; i < 4; ++i) {
        const int col = nn + cc * 4;
        float4 v = {acc[i][0] + bia[col], acc[i][1] + bia[col + 1],
                    acc[i][2] + bia[col + 2], acc[i][3] + bia[col + 3]};
        st4(xwd + (size_t)(m0 + cr * 4 + i) * 2048 + n0 + cc * 4, v);
    }
}

__global__ __launch_bounds__(256) void dense_kernel(
    const float* __restrict__ hseq, const float* __restrict__ Dk,
    const float* __restrict__ Db, float* __restrict__ out)
{
    __shared__ float dk[8192];
    for (int i = threadIdx.x; i < 8192; i += 256) dk[i] = Dk[i];
    __syncthreads();
    const int f = threadIdx.x & 15;
    const int bt = blockIdx.x * 16 + (threadIdx.x >> 4);
    const float* hs = hseq + (size_t)bt * 512;
    float acc = Db[f];
    #pragma unroll 4
    for (int k = 0; k < 512; k += 4) {
        const float4 hv = ld4(hs + k);
        acc += hv.x * dk[(k + 0) * 16 + f] + hv.y * dk[(k + 1) * 16 + f]
             + hv.z * dk[(k + 2) * 16 + f] + hv.w * dk[(k + 3) * 16 + f];
    }
    out[(size_t)bt * 16 + f] = acc;
}

// ---------------------------------------------------------------------------
extern "C" void kernel_launch(void* const* d_in, const int* in_sizes, int n_in,
                              void* d_out, int out_size, void* d_ws, size_t ws_size,
                              hipStream_t stream)
{
    const float* x    = (const float*)d_in[0];
    const float* encW = (const float*)d_in[1];
    const float* encU = (const float*)d_in[2];
    const float* encB = (const float*)d_in[3];
    const float* dfK  = (const float*)d_in[4];
    const float* dfU  = (const float*)d_in[5];
    const float* dfB  = (const float*)d_in[6];
    const float* dbK  = (const float*)d_in[7];
    const float* dbU  = (const float*)d_in[8];
    const float* dbB  = (const float*)d_in[9];
    const float* dK   = (const float*)d_in[10];
    const float* dB   = (const float*)d_in[11];

    if (ws_size < WS_FLOATS * sizeof(float)) return;

    float* ws   = (float*)d_ws;
    short* bh   = (short*)ws;                    // 1,179,648 shorts
    short* bl   = bh + 1179648;                  // 1,179,648 shorts
    float* hseq = ws;                            // alias (decoder phase only)
    float* zenc = ws + OFS_ZENC;
    float* cenc = ws + OFS_CENC;
    float* henc = ws + OFS_HENC;
    short* hfh  = (short*)(ws + OFS_HFRAG);      // 131,072 shorts
    short* hfl  = hfh + 131072;
    float* xwd  = ws + OFS_XWD;
    float* zdec = ws + OFS_ZDEC;
    float* cdec = ws + OFS_CDEC;

    // one-time (per call) weight fragment packing
    bfrag_prep<<<dim3(36, 64), 64, 0, stream>>>(encW, encU, bh, bl);

    // ---- encoder: 256 steps, 2 launches each ----
    for (int t = 0; t < 256; ++t) {
        enc_gemm<<<dim3(32, 8), 128, 0, stream>>>(x, bh, bl, hfh, hfl, zenc, t);
        enc_upd<<<256, 64, 0, stream>>>(zenc, encB, cenc, henc, hfh, hfl, t);
    }

    // ---- decoder ----
    dec_proj<<<dim3(32, 8), 128, 0, stream>>>(henc, dfK, dbK, dfB, dbB, xwd);
    for (int s = 1; s <= 64; ++s)
        dec_step<<<256, 256, 0, stream>>>(dfU, dbU, xwd, zdec, cdec, hseq, s);

    dense_kernel<<<1024, 256, 0, stream>>>(hseq, dK, dB, (float*)d_out);
}